// Round 1
// baseline (7655.972 us; speedup 1.0000x reference)
//
#include <hip/hip_runtime.h>
#include <hip/hip_cooperative_groups.h>

namespace cg = cooperative_groups;

// Problem constants (match reference setup_inputs)
constexpr int L = 64;
constexpr int P = 32768;
constexpr int N = L * P;          // 2,097,152 nodes
constexpr int E_PER = 262144;     // edges per non-source level
constexpr int NLEVELS = L - 1;    // 63 edge levels

constexpr int BLOCK = 256;
constexpr int GRID  = E_PER / BLOCK;   // 1024 blocks -> 4 blocks/CU on 256 CUs

// Single persistent cooperative kernel:
//   phase 0: out = hdr (vectorized copy, 2x float4 per thread)
//   then 63 levels, separated by grid.sync() instead of kernel boundaries.
// Correctness notes:
//  - src of level l lies in [0, l*P), dst in [l*P, (l+1)*P): disjoint within a
//    level, so the gather and the scatter-atomic never race inside a level.
//  - each dst node is written only at its own level; init value 0 < cand (>=1),
//    so atomicMax == reference's replace-with-cand semantics.
//  - all values non-negative floats -> uint bit-pattern atomicMax is exact.
//  - grid.sync() carries device-scope release/acquire fences, making the
//    device-scope atomics of level l visible to level l+1's plain gathers
//    across XCDs.
__global__ void __launch_bounds__(BLOCK, 4)
pathfinder_fused(const float4* __restrict__ hdr4,
                 const int* __restrict__ src,
                 const int* __restrict__ dst,
                 float* __restrict__ out) {
    const int t = blockIdx.x * BLOCK + threadIdx.x;   // 0 .. E_PER-1
    cg::grid_group grid = cg::this_grid();

    // Phase 0: out = hdr. N/4 = 524288 float4s, 2 per thread, fully coalesced.
    {
        float4* __restrict__ out4 = reinterpret_cast<float4*>(out);
        out4[t]         = hdr4[t];
        out4[t + E_PER] = hdr4[t + E_PER];
    }

    // Preload level-0 edge endpoints (coalesced).
    int si = src[t];
    int di = dst[t];

    grid.sync();   // out fully initialized & visible grid-wide

    for (int l = 0; l < NLEVELS; ++l) {
        // Gather from earlier levels (L2/L3-resident), relax to fire-and-forget
        // scatter-max on the current level's slice.
        const float v = out[si] + 1.0f;
        atomicMax(reinterpret_cast<unsigned int*>(out) + di,
                  __float_as_uint(v));

        // Software pipeline: issue next level's coalesced edge loads BEFORE the
        // barrier so their latency hides under the sync spin. (These are plain
        // loads of read-only data; safe to hoist across the level boundary.)
        if (l + 1 < NLEVELS) {
            const size_t base = (size_t)(l + 1) * E_PER;
            si = src[base + t];
            di = dst[base + t];
        }

        grid.sync();   // level l's atomics visible before level l+1 gathers
    }
}

extern "C" void kernel_launch(void* const* d_in, const int* in_sizes, int n_in,
                              void* d_out, int out_size, void* d_ws, size_t ws_size,
                              hipStream_t stream) {
    const float4* hdr4 = (const float4*)d_in[0];
    const int*    src  = (const int*)d_in[1];
    const int*    dst  = (const int*)d_in[2];
    float*        out  = (float*)d_out;

    void* args[] = { (void*)&hdr4, (void*)&src, (void*)&dst, (void*)&out };
    hipLaunchCooperativeKernel((const void*)pathfinder_fused,
                               dim3(GRID), dim3(BLOCK), args, 0, stream);
}

// Round 2
// 3665.929 us; speedup vs baseline: 2.0884x; 2.0884x over previous
//
#include <hip/hip_runtime.h>

// Problem constants (match reference setup_inputs)
constexpr int L = 64;
constexpr int P = 32768;
constexpr int N = L * P;          // 2,097,152 nodes
constexpr int E_PER = 262144;     // edges per non-source level
constexpr int NLEVELS = L - 1;    // 63 edge levels

constexpr int BLOCK = 256;
constexpr int GRID  = E_PER / BLOCK;       // 1024 blocks -> 4/CU, 16 waves/CU
constexpr int GROUPS = 32;                 // barrier arrival fan-in
constexpr int GROUP_SIZE = GRID / GROUPS;  // 32 blocks per group
constexpr int SLOT = 32;                   // uints per counter slot = 128 B (own line)

// Workspace layout (uint slots, each 128 B apart):
//   slot 0            : global arrival counter
//   slots 1..32       : per-group arrival counters
//   slots 33..64      : per-group release flags
// All counters are MONOTONE across the 63 barriers (targets scale with level),
// so no in-run reset -> no ABA. ws_init re-zeroes before each replay.
__global__ void __launch_bounds__(256)
ws_init(unsigned* __restrict__ ws) {
    for (int k = threadIdx.x; k < (1 + 2 * GROUPS) * SLOT; k += 256) ws[k] = 0u;
}

// Persistent kernel: init copy + 63 levels separated by a hand-rolled
// hierarchical grid barrier (replaces ROCm cg::grid_group::sync, which
// measured ~117 us per sync in R1).
// Correctness (validated bit-exact by the cg version in R1):
//  - src of level l in [0, l*P), dst in [l*P,(l+1)*P): no intra-level race.
//  - non-negative floats -> uint-pattern atomicMax is exact max.
//  - __threadfence() at agent scope performs L2 writeback (release) /
//    cache invalidate (acquire), giving cross-XCD visibility of the
//    device-scope atomicMax results and the init stores.
__global__ void __launch_bounds__(BLOCK, 4)
pathfinder_fused(const float4* __restrict__ hdr4,
                 const int* __restrict__ src,
                 const int* __restrict__ dst,
                 float* __restrict__ out,
                 unsigned* __restrict__ ws) {
    const int b = blockIdx.x;
    const int t = b * BLOCK + threadIdx.x;   // 0 .. E_PER-1
    const int g = b / GROUP_SIZE;

    unsigned* const gcnt   = ws;                            // global counter
    unsigned* const grpcnt = ws + (1 + g) * SLOT;           // my group's counter
    unsigned* const grprel = ws + (1 + GROUPS + g) * SLOT;  // my group's release

    // Phase 0: out = hdr. N/4 float4s, 2 per thread, fully coalesced.
    {
        float4* __restrict__ out4 = reinterpret_cast<float4*>(out);
        out4[t]         = hdr4[t];
        out4[t + E_PER] = hdr4[t + E_PER];
    }

    // Preload level-0 edge endpoints (coalesced).
    int si = src[t];
    int di = dst[t];

    for (int l = 0; l < NLEVELS; ++l) {
        // ---- grid barrier #l (covers init for l==0, level l-1 atomics after) ----
        __syncthreads();
        if (threadIdx.x == 0) {
            __threadfence();   // release: write back local L2, publish atomics
            const unsigned old = __hip_atomic_fetch_add(
                grpcnt, 1u, __ATOMIC_RELAXED, __HIP_MEMORY_SCOPE_AGENT);
            if (old == (unsigned)((l + 1) * GROUP_SIZE - 1)) {
                // last block of my group for this barrier
                const unsigned o2 = __hip_atomic_fetch_add(
                    gcnt, 1u, __ATOMIC_RELAXED, __HIP_MEMORY_SCOPE_AGENT);
                if (o2 == (unsigned)((l + 1) * GROUPS - 1)) {
                    // last group overall: fan out release to all 32 group flags
                    #pragma unroll
                    for (int g2 = 0; g2 < GROUPS; ++g2)
                        __hip_atomic_store(ws + (1 + GROUPS + g2) * SLOT,
                                           (unsigned)(l + 1), __ATOMIC_RELAXED,
                                           __HIP_MEMORY_SCOPE_AGENT);
                }
            }
            // spin on my group's flag (<=32 spinners per line, not 1024)
            while (__hip_atomic_load(grprel, __ATOMIC_RELAXED,
                                     __HIP_MEMORY_SCOPE_AGENT)
                   < (unsigned)(l + 1)) {
                __builtin_amdgcn_s_sleep(1);
            }
            __threadfence();   // acquire: invalidate stale L1/L2 lines
        }
        __syncthreads();

        // Level l work: gather from earlier levels, scatter-max into level l.
        const float v = out[si] + 1.0f;
        atomicMax(reinterpret_cast<unsigned*>(out) + di, __float_as_uint(v));

        // Preload next level's edges; stays in flight across the next barrier.
        if (l + 1 < NLEVELS) {
            const size_t base = (size_t)(l + 1) * E_PER;
            si = src[base + t];
            di = dst[base + t];
        }
    }
    // No trailing barrier: end-of-kernel release makes level-62 atomics
    // visible to the host/output copy.
}

extern "C" void kernel_launch(void* const* d_in, const int* in_sizes, int n_in,
                              void* d_out, int out_size, void* d_ws, size_t ws_size,
                              hipStream_t stream) {
    const float4* hdr4 = (const float4*)d_in[0];
    const int*    src  = (const int*)d_in[1];
    const int*    dst  = (const int*)d_in[2];
    float*        out  = (float*)d_out;
    unsigned*     ws   = (unsigned*)d_ws;

    // Zero the barrier counters (stream-ordered before the main kernel).
    ws_init<<<dim3(1), dim3(256), 0, stream>>>(ws);

    void* args[] = { (void*)&hdr4, (void*)&src, (void*)&dst,
                     (void*)&out, (void*)&ws };
    hipLaunchCooperativeKernel((const void*)pathfinder_fused,
                               dim3(GRID), dim3(BLOCK), args, 0, stream);
}

// Round 3
// 931.960 us; speedup vs baseline: 8.2149x; 3.9336x over previous
//
#include <hip/hip_runtime.h>

// Problem constants (match reference setup_inputs)
constexpr int L = 64;
constexpr int P = 32768;
constexpr int N = L * P;          // 2,097,152 nodes
constexpr int E_PER = 262144;     // edges per non-source level
constexpr int NLEVELS = L - 1;    // 63 edge levels

constexpr int BLOCK = 256;
constexpr int GRID  = E_PER / BLOCK;       // 1024 blocks -> 4/CU, 16 waves/CU
constexpr int GROUPS = 32;                 // barrier arrival fan-in
constexpr int GROUP_SIZE = GRID / GROUPS;  // 32 blocks per group
constexpr int SLOT = 32;                   // uints per slot = 128 B (own line)

// Workspace layout (uint slots, 128 B apart):
//   slot 0      : global arrival counter
//   slots 1..32 : per-group arrival counters
//   slots 33..64: per-group release flags
// Counters are MONOTONE across the 63 barriers (no reset -> no ABA);
// ws_init re-zeroes before each replay.
__global__ void __launch_bounds__(256)
ws_init(unsigned* __restrict__ ws) {
    for (int k = threadIdx.x; k < (1 + 2 * GROUPS) * SLOT; k += 256) ws[k] = 0u;
}

// Persistent kernel, fence-free barriers.
// Coherence scheme (replaces R2's per-level threadfence = full L2 wb+inv):
//  - atomicMax (agent scope) executes at the cross-XCD coherence point
//    (proven by R2's cross-XCD same-address correctness).
//  - gather loads of `out` are relaxed AGENT-scope atomic loads -> sc1,
//    bypass the non-coherent per-XCD L2 and read the coherence point
//    (L3-resident, out is only 8 MB). No cache invalidate needed.
//  - plain init stores are published ONCE via __threadfence at barrier 0.
//  - "my atomics complete before my arrival": __syncthreads() drains each
//    wave's vmem (compiler emits s_waitcnt vmcnt(0) before s_barrier).
__global__ void __launch_bounds__(BLOCK, 4)
pathfinder_fused(const float4* __restrict__ hdr4,
                 const int* __restrict__ src,
                 const int* __restrict__ dst,
                 float* __restrict__ out,
                 unsigned* __restrict__ ws) {
    const int b = blockIdx.x;
    const int t = b * BLOCK + threadIdx.x;   // 0 .. E_PER-1
    const int g = b / GROUP_SIZE;

    unsigned* const gcnt   = ws;                            // global counter
    unsigned* const grpcnt = ws + (1 + g) * SLOT;           // my group's counter
    unsigned* const grprel = ws + (1 + GROUPS + g) * SLOT;  // my group's release

    // Phase 0: out = hdr. N/4 float4s, 2 per thread, fully coalesced.
    {
        float4* __restrict__ out4 = reinterpret_cast<float4*>(out);
        out4[t]         = hdr4[t];
        out4[t + E_PER] = hdr4[t + E_PER];
    }

    // Preload level-0 edge endpoints (coalesced, read-only -> plain loads).
    int si = src[t];
    int di = dst[t];

    unsigned* const outu = reinterpret_cast<unsigned*>(out);

    for (int l = 0; l < NLEVELS; ++l) {
        // ---- grid barrier #l (fence-free except l==0 init publish) ----
        __syncthreads();   // drains this block's stores/atomics (vmcnt(0))
        if (threadIdx.x == 0) {
            if (l == 0) __threadfence();   // once: write back init stores (wbl2)
            const unsigned old = __hip_atomic_fetch_add(
                grpcnt, 1u, __ATOMIC_RELAXED, __HIP_MEMORY_SCOPE_AGENT);
            if (old == (unsigned)((l + 1) * GROUP_SIZE - 1)) {
                const unsigned o2 = __hip_atomic_fetch_add(
                    gcnt, 1u, __ATOMIC_RELAXED, __HIP_MEMORY_SCOPE_AGENT);
                if (o2 == (unsigned)((l + 1) * GROUPS - 1)) {
                    // last block overall: fan out release to 32 group flags
                    #pragma unroll
                    for (int g2 = 0; g2 < GROUPS; ++g2)
                        __hip_atomic_store(ws + (1 + GROUPS + g2) * SLOT,
                                           (unsigned)(l + 1), __ATOMIC_RELAXED,
                                           __HIP_MEMORY_SCOPE_AGENT);
                }
            }
            // spin on my group's flag (coherent load; <=32 spinners/line)
            while (__hip_atomic_load(grprel, __ATOMIC_RELAXED,
                                     __HIP_MEMORY_SCOPE_AGENT)
                   < (unsigned)(l + 1)) {
                __builtin_amdgcn_s_sleep(1);
            }
        }
        __syncthreads();

        // Level l work: coherent gather (bypasses stale L2), scatter-max.
        const unsigned raw = __hip_atomic_load(
            outu + si, __ATOMIC_RELAXED, __HIP_MEMORY_SCOPE_AGENT);
        const float v = __uint_as_float(raw) + 1.0f;
        atomicMax(outu + di, __float_as_uint(v));

        // Preload next level's edges (read-only; safe across the barrier).
        if (l + 1 < NLEVELS) {
            const size_t base = (size_t)(l + 1) * E_PER;
            si = src[base + t];
            di = dst[base + t];
        }
    }
    // Kernel-end implicit system-scope release publishes the final atomics.
}

extern "C" void kernel_launch(void* const* d_in, const int* in_sizes, int n_in,
                              void* d_out, int out_size, void* d_ws, size_t ws_size,
                              hipStream_t stream) {
    const float4* hdr4 = (const float4*)d_in[0];
    const int*    src  = (const int*)d_in[1];
    const int*    dst  = (const int*)d_in[2];
    float*        out  = (float*)d_out;
    unsigned*     ws   = (unsigned*)d_ws;

    // Zero barrier counters (stream-ordered before the main kernel).
    ws_init<<<dim3(1), dim3(256), 0, stream>>>(ws);

    void* args[] = { (void*)&hdr4, (void*)&src, (void*)&dst,
                     (void*)&out, (void*)&ws };
    hipLaunchCooperativeKernel((const void*)pathfinder_fused,
                               dim3(GRID), dim3(BLOCK), args, 0, stream);
}